// Round 1
// 586.585 us; speedup vs baseline: 1.1384x; 1.1384x over previous
//
#include <hip/hip_runtime.h>
#include <cstdint>
#include <cstddef>

#define DD 2048
#define LL 2048
#define BB 4
#define MM (BB * LL) // 8192
#define NN 6144      // fused q|k|v output columns

typedef __bf16 bf16;
typedef __bf16 bf16x8 __attribute__((ext_vector_type(8)));
typedef __bf16 bf16x4 __attribute__((ext_vector_type(4)));
typedef __bf16 bf16x2 __attribute__((ext_vector_type(2)));
typedef float f32x4 __attribute__((ext_vector_type(4)));

// ---------------------------------------------------------------------------
// async global -> LDS, 16B per lane (wave-uniform base + lane*16 layout)
// ---------------------------------------------------------------------------
__device__ __forceinline__ void gload16(const void* g, void* l) {
    __builtin_amdgcn_global_load_lds(
        (const __attribute__((address_space(1))) void*)g,
        (__attribute__((address_space(3))) void*)l, 16, 0, 0);
}

// ---------------------------------------------------------------------------
// fp32 -> bf16 conversion (8 elements/thread)
// ---------------------------------------------------------------------------
__global__ __launch_bounds__(256) void cvt_f32_bf16(const float* __restrict__ s,
                                                    bf16* __restrict__ d, int n8) {
    int i = blockIdx.x * 256 + threadIdx.x;
    if (i >= n8) return;
    const float4* sp = (const float4*)s + (size_t)i * 2;
    float4 a = sp[0], b = sp[1];
    bf16x8 o;
    o[0] = (bf16)a.x; o[1] = (bf16)a.y; o[2] = (bf16)a.z; o[3] = (bf16)a.w;
    o[4] = (bf16)b.x; o[5] = (bf16)b.y; o[6] = (bf16)b.z; o[7] = (bf16)b.w;
    *((bf16x8*)d + i) = o;
}

// ---------------------------------------------------------------------------
// 256x256 8-wave deep-pipelined K-loop (BK=64, 2 LDS buffers = 128 KiB).
// Schedule: 4 phases per K-tile, counted vmcnt(4) at phases 0/2 (never 0 in
// main loop), 2 barriers/phase, setprio(1) around each 16-MFMA cluster.
// Staging order per tile: A-h0, B-h0, A-h1, B-h1 (2 global_load_lds each);
// phases 0/1 consume only K-half 0, phases 2/3 only K-half 1, so vmcnt(4)
// (= keep 2 newest half-stages in flight) exactly covers the half about to
// be read. LDS fragment layout is XOR-swizzled (slot = fg ^ ((row>>1)&3))
// via pre-swizzled GLOBAL source addresses (global_load_lds writes linearly)
// + the same swizzle on the ds_read side -> 2-way residual conflicts (free).
//
// LDS map (bf16 idx): A0 [0,16384) A1 [16384,32768) B0 [32768,49152) B1 [49152,65536)
// Within a buffer: half h at h*8192; row r at r*32; 4 chunks of 8 elems.
// ---------------------------------------------------------------------------
__device__ __forceinline__ void stage_half(const bf16* g, bf16* l, size_t rstep, int tid) {
    gload16(g, l + tid * 8);
    gload16(g + rstep, l + 4096 + tid * 8);
}

#define MFMA16(J0, J1)                                                         \
    __builtin_amdgcn_s_setprio(1);                                             \
    _Pragma("unroll") for (int i = 0; i < 8; i++)                              \
        acc[i][J0] = __builtin_amdgcn_mfma_f32_16x16x32_bf16(af[i], bq[J0],    \
                                                             acc[i][J0], 0, 0, 0); \
    _Pragma("unroll") for (int i = 0; i < 8; i++)                              \
        acc[i][J1] = __builtin_amdgcn_mfma_f32_16x16x32_bf16(af[i], bq[J1],    \
                                                             acc[i][J1], 0, 0, 0); \
    __builtin_amdgcn_s_setprio(0);

template <int NT>
__device__ __forceinline__ void mma256_loop(const bf16* gA, const bf16* gB,
                                            int Kdim, bf16* lds,
                                            f32x4 (&acc)[8][4]) {
    const int tid = threadIdx.x;
    const int wave = tid >> 6, lane = tid & 63;
    const int wm = wave >> 2, wn = wave & 3;     // 2 x 4 wave grid
    const int fm = lane & 15, fg = lane >> 4;
    const size_t rstep = (size_t)128 * Kdim;
    // per-lane swizzled chunk offset for fragment reads (involution w/ staging)
    const int koff = ((fg ^ ((fm >> 1) & 3)) << 3);
    const int aoff = (wm * 128 + fm) * 32 + koff;
    const int boff = (wn * 64 + fm) * 32 + koff;

    bf16* const A0 = lds;
    bf16* const B0 = lds + 32768;

#pragma unroll
    for (int i = 0; i < 8; i++)
#pragma unroll
        for (int j = 0; j < 4; j++) acc[i][j] = (f32x4){0.f, 0.f, 0.f, 0.f};

    // prologue: stage tile 0 -> buf0 (issue order = consume order)
    stage_half(gA, A0, rstep, tid);
    stage_half(gB, B0, rstep, tid);
    stage_half(gA + 32, A0 + 8192, rstep, tid);
    stage_half(gB + 32, B0 + 8192, rstep, tid);

    bf16x8 af[8], bq[4];

    for (int t = 0; t < NT; ++t) {
        const int c = t & 1;
        bf16* const Ac = A0 + c * 16384;
        bf16* const Bc = B0 + c * 16384;
        bf16* const An = A0 + (c ^ 1) * 16384;
        bf16* const Bn = B0 + (c ^ 1) * 16384;
        const bf16* a1 = gA + (t + 1) * 64;
        const bf16* b1 = gB + (t + 1) * 64;
        const bool st = (t + 1 < NT);

        // ---- P0: h=0, j=0,1 ----
        asm volatile("s_waitcnt vmcnt(4)" ::: "memory"); // tile-t h0 resident
        __builtin_amdgcn_s_barrier();
        if (st) stage_half(a1, An, rstep, tid); // A-h0 of t+1
#pragma unroll
        for (int i = 0; i < 8; i++) af[i] = *(const bf16x8*)(Ac + aoff + i * 512);
        bq[0] = *(const bf16x8*)(Bc + boff);
        bq[1] = *(const bf16x8*)(Bc + boff + 512);
        __builtin_amdgcn_s_barrier();
        asm volatile("s_waitcnt lgkmcnt(0)" ::: "memory");
        MFMA16(0, 1)

        // ---- P1: h=0, j=2,3 ----
        __builtin_amdgcn_s_barrier();
        if (st) stage_half(b1, Bn, rstep, tid); // B-h0 of t+1
        bq[2] = *(const bf16x8*)(Bc + boff + 1024);
        bq[3] = *(const bf16x8*)(Bc + boff + 1536);
        __builtin_amdgcn_s_barrier();
        asm volatile("s_waitcnt lgkmcnt(0)" ::: "memory");
        MFMA16(2, 3)

        // ---- P2: h=1, j=0,1 ----
        if (st) { asm volatile("s_waitcnt vmcnt(4)" ::: "memory"); } // tile-t h1 resident
        else    { asm volatile("s_waitcnt vmcnt(0)" ::: "memory"); } // last tile: drain
        __builtin_amdgcn_s_barrier();
        if (st) stage_half(a1 + 32, An + 8192, rstep, tid); // A-h1 of t+1
#pragma unroll
        for (int i = 0; i < 8; i++) af[i] = *(const bf16x8*)(Ac + 8192 + aoff + i * 512);
        bq[0] = *(const bf16x8*)(Bc + 8192 + boff);
        bq[1] = *(const bf16x8*)(Bc + 8192 + boff + 512);
        __builtin_amdgcn_s_barrier();
        asm volatile("s_waitcnt lgkmcnt(0)" ::: "memory");
        MFMA16(0, 1)

        // ---- P3: h=1, j=2,3 ----
        __builtin_amdgcn_s_barrier();
        if (st) stage_half(b1 + 32, Bn + 8192, rstep, tid); // B-h1 of t+1
        bq[2] = *(const bf16x8*)(Bc + 8192 + boff + 1024);
        bq[3] = *(const bf16x8*)(Bc + 8192 + boff + 1536);
        __builtin_amdgcn_s_barrier();
        asm volatile("s_waitcnt lgkmcnt(0)" ::: "memory");
        MFMA16(2, 3)
    }
}

// ---------------------------------------------------------------------------
// Fused QKV GEMM: C[m,n] = sum_k A[m,k]*Wqkv[n,k] + bias(n), written
// TRANSPOSED: out[n][m] (bf16, (6144, 8192)).  256x256 tile, 8-phase pipe.
// Epilogue stages the C-tile into the full 128 KiB LDS as Ct[col][row] with a
// row-XOR swizzle (no pad possible at 256x256), then stores 512B-contiguous
// runs of C^T.
// ---------------------------------------------------------------------------
__global__ __launch_bounds__(512, 2) void gemm_qkv(const bf16* __restrict__ A,
                                                   const bf16* __restrict__ Bm,
                                                   const float* __restrict__ bqp,
                                                   const float* __restrict__ bkp,
                                                   const float* __restrict__ bvp,
                                                   bf16* __restrict__ CtOut) {
    __shared__ bf16 lds[65536]; // 128 KiB: A/B double buffers, then C-stage
    // XCD-aware swizzle: nwg = 768 (%8 == 0), m-fast within each XCD chunk
    const int id = blockIdx.x;
    const int wg = (id & 7) * 96 + (id >> 3);
    const int m0 = (wg & 31) << 8;  // Mt = 32
    const int n0 = (wg >> 5) << 8;  // Nt = 24

    const int tid = threadIdx.x;
    const int wave = tid >> 6, lane = tid & 63;
    // staging source (pre-swizzled global address; LDS dest stays linear)
    const int srow = tid >> 2;                                   // 0..127
    const int skx = (((lane & 3) ^ ((lane >> 3) & 3)) << 3);     // swizzled chunk
    const bf16* gA = A + (size_t)(m0 + srow) * DD + skx;
    const bf16* gB = Bm + (size_t)(n0 + srow) * DD + skx;

    f32x4 acc[8][4];
    mma256_loop<DD / 64>(gA, gB, DD, lds, acc);

    // ---- epilogue: bias + transposed store via swizzled LDS C-stage ----
    __syncthreads(); // loop fully drained; safe to reuse LDS
    const int wm = wave >> 2, wn = wave & 3;
    const int fm = lane & 15, fg = lane >> 4;
    const float* bp = (n0 < 2048) ? bqp : ((n0 < 4096) ? bkp : bvp);
    const int nb = n0 & 2047;
#pragma unroll
    for (int j = 0; j < 4; j++) {
        const int col = wn * 64 + j * 16 + fm;
        const float bvv = bp[nb + col];
        const int csw = (col & 7) << 3;
#pragma unroll
        for (int i = 0; i < 8; i++) {
            const int row = (wm * 128 + i * 16 + fg * 4) ^ csw; // bits>=3 only
            bf16x4 o;
#pragma unroll
            for (int r = 0; r < 4; r++) o[r] = (bf16)(acc[i][j][r] + bvv);
            *(bf16x4*)&lds[col * 256 + row] = o;
        }
    }
    __syncthreads();
    const int ccol = tid >> 5, chunk = tid & 31;
#pragma unroll
    for (int p = 0; p < 16; p++) {
        const int col = p * 16 + ccol;
        bf16x8 vv = *(const bf16x8*)&lds[col * 256 + ((chunk * 8) ^ ((col & 7) << 3))];
        *(bf16x8*)(CtOut + (size_t)(n0 + col) * MM + m0 + chunk * 8) = vv;
    }
}

// ---------------------------------------------------------------------------
// Output projection GEMM (row-major f32 out): C[m,n] = sum_k A[m,k]*B[n,k]+b[n]
// Same 256x256 8-phase pipeline, direct f32 epilogue.
// ---------------------------------------------------------------------------
__global__ __launch_bounds__(512, 2) void gemm_bt_f32(const bf16* __restrict__ A,
                                                      const bf16* __restrict__ Bm,
                                                      const float* __restrict__ bias,
                                                      float* __restrict__ C,
                                                      int Ndim, int Kdim) {
    __shared__ bf16 lds[65536];
    const int id = blockIdx.x;
    const int wg = (id & 7) * (gridDim.x >> 3) + (id >> 3);
    const int m0 = (wg & 31) << 8;  // Mt = 32
    const int n0 = (wg >> 5) << 8;

    const int tid = threadIdx.x;
    const int wave = tid >> 6, lane = tid & 63;
    const int srow = tid >> 2;
    const int skx = (((lane & 3) ^ ((lane >> 3) & 3)) << 3);
    const bf16* gA = A + (size_t)(m0 + srow) * Kdim + skx;
    const bf16* gB = Bm + (size_t)(n0 + srow) * Kdim + skx;

    f32x4 acc[8][4];
    mma256_loop<DD / 64>(gA, gB, Kdim, lds, acc);

    const int wm = wave >> 2, wn = wave & 3;
    const int fm = lane & 15, fg = lane >> 4;
#pragma unroll
    for (int j = 0; j < 4; j++) {
        const int col = n0 + wn * 64 + j * 16 + fm;
        const float bvv = bias[col];
#pragma unroll
        for (int i = 0; i < 8; i++) {
#pragma unroll
            for (int r = 0; r < 4; r++) {
                const int row = m0 + wm * 128 + i * 16 + fg * 4 + r;
                C[(size_t)row * Ndim + col] = acc[i][j][r] + bvv;
            }
        }
    }
}

// ---------------------------------------------------------------------------
// Depthwise causal conv (width 3) on qT/kT rows + kv=conv(k)*v.  (unchanged)
// ---------------------------------------------------------------------------
__global__ __launch_bounds__(256) void dwconv_kv2(
    const bf16* __restrict__ qkvT,
    const float* __restrict__ cqw, const float* __restrict__ cqb,
    const float* __restrict__ ckw, const float* __restrict__ ckb,
    bf16* __restrict__ qcT, bf16* __restrict__ kvT) {
    const int bid = blockIdx.x;
    const int b = bid >> 11, d = bid & (DD - 1);
    const int tid = threadIdx.x;
    const int l = tid * 8;

    const bf16* qR = qkvT + (size_t)d * MM + b * LL;
    const bf16* kR = qkvT + (size_t)(2048 + d) * MM + b * LL;
    const bf16* vR = qkvT + (size_t)(4096 + d) * MM + b * LL;

    const float q0 = cqw[d * 3], q1 = cqw[d * 3 + 1], q2 = cqw[d * 3 + 2];
    const float k0 = ckw[d * 3], k1 = ckw[d * 3 + 1], k2 = ckw[d * 3 + 2];
    const float qb = cqb[d], kb = ckb[d];

    bf16x8 qx = *(const bf16x8*)(qR + l);
    bf16x8 kx = *(const bf16x8*)(kR + l);
    bf16x8 vx = *(const bf16x8*)(vR + l);

    float xq[10], xk[10];
    xq[0] = 0.f; xq[1] = 0.f; xk[0] = 0.f; xk[1] = 0.f;
    if (l >= 2) {
        bf16x2 qh = *(const bf16x2*)(qR + l - 2);
        bf16x2 kh = *(const bf16x2*)(kR + l - 2);
        xq[0] = (float)qh[0]; xq[1] = (float)qh[1];
        xk[0] = (float)kh[0]; xk[1] = (float)kh[1];
    }
#pragma unroll
    for (int c = 0; c < 8; c++) { xq[c + 2] = (float)qx[c]; xk[c + 2] = (float)kx[c]; }

    bf16x8 oq, okv;
#pragma unroll
    for (int c = 0; c < 8; c++) {
        float qc = q0 * xq[c] + q1 * xq[c + 1] + q2 * xq[c + 2] + qb;
        float kc = k0 * xk[c] + k1 * xk[c + 1] + k2 * xk[c + 2] + kb;
        oq[c] = (bf16)qc;
        okv[c] = (bf16)(kc * (float)vx[c]);
    }
    const size_t o = ((size_t)b * DD + d) * LL + l;
    *(bf16x8*)(qcT + o) = oq;
    *(bf16x8*)(kvT + o) = okv;
}

// ---------------------------------------------------------------------------
// Causal long conv + D-skip + q gating via Toeplitz MFMA.  (unchanged)
// ---------------------------------------------------------------------------
__global__ __launch_bounds__(128, 2) void longconv_gate(
    const bf16* __restrict__ kvT, const bf16* __restrict__ qcT,
    const float* __restrict__ kern, const float* __restrict__ Dskip,
    bf16* __restrict__ ygT) {
    __shared__ bf16 kv_ls[4 * 2112];
    __shared__ float krev_f[2112];
    const int d = blockIdx.x;
    const int tid = threadIdx.x;

    {
        const int bb = tid >> 5, t32 = tid & 31;
#pragma unroll
        for (int c = 0; c < 8; ++c) {
            const int l = (c * 32 + t32) * 8;
            bf16x8 v = *(const bf16x8*)(kvT + ((size_t)bb * DD + d) * LL + l);
            *(bf16x8*)&kv_ls[2112 * bb + 48 + l] = v;
        }
        if (tid < 48) {
#pragma unroll
            for (int b2 = 0; b2 < 4; b2++) kv_ls[2112 * b2 + tid] = (bf16)0.f;
        } else if (tid < 64) {
#pragma unroll
            for (int b2 = 0; b2 < 4; b2++) kv_ls[2112 * b2 + 2048 + tid] = (bf16)0.f;
        }
    }
    {
        const float* kr = kern + (size_t)d * LL;
#pragma unroll
        for (int c = 0; c < 16; ++c) {
            const int x = c * 128 + tid;
            krev_f[x] = kr[2047 - x];
        }
        if (tid < 64) krev_f[2048 + tid] = 0.f;
    }
    __syncthreads();

    const int lane = tid & 63;
    const int w = __builtin_amdgcn_readfirstlane(tid >> 6);
    const int n = lane & 15, q = lane >> 4;
    const int b = n & 3, pp = n >> 2;
    const int cB = 2112 * b + 16 * pp + 8 * q;

    f32x4 acc[16];
#pragma unroll
    for (int s = 0; s < 16; s++) acc[s] = (f32x4){0.f, 0.f, 0.f, 0.f};

    for (int it = 0; it < 64; ++it) {
        const int as = 2031 - 32 * it - n + 8 * q;
        float af[8];
#pragma unroll
        for (int j = 0; j < 8; j++) af[j] = krev_f[as + j];
        bf16x8 a;
#pragma unroll
        for (int j = 0; j < 8; j++) a[j] = (bf16)af[j];

        const int bbase = cB + 64 * w + 32 - 32 * it;
#pragma unroll
        for (int h = 0; h < 2; ++h) {
            bf16x8 bfr[8];
#pragma unroll
            for (int s8 = 0; s8 < 8; s8++) {
                const int s = h * 8 + s8;
                if (it <= 4 * s + 2 * w + 1)
                    bfr[s8] = *(const bf16x8*)&kv_ls[bbase + 128 * s];
            }
#pragma unroll
            for (int s8 = 0; s8 < 8; s8++) {
                const int s = h * 8 + s8;
                if (it <= 4 * s + 2 * w + 1)
                    acc[s] = __builtin_amdgcn_mfma_f32_16x16x32_bf16(
                        a, bfr[s8], acc[s], 0, 0, 0);
            }
        }
    }

    const float dsk = Dskip[d];
#pragma unroll
    for (int s = 0; s < 16; s++) {
        const int i = 2 * s + w;
        const int l = 64 * i + 16 * pp + 4 * q;
        const size_t gb = ((size_t)b * DD + d) * LL + l;
        bf16x4 qc4 = *(const bf16x4*)&qcT[gb];
        bf16x4 kv4 = *(const bf16x4*)&kv_ls[2112 * b + 48 + l];
        bf16x4 o;
#pragma unroll
        for (int r = 0; r < 4; r++) {
            float val = (acc[s][r] + (float)kv4[r] * dsk) * (float)qc4[r];
            o[r] = (bf16)val;
        }
        *(bf16x4*)&ygT[gb] = o;
    }
}

// ---------------------------------------------------------------------------
// bf16 transpose (B, D, L) -> (B, L, D), 32x32 tiles (unchanged)
// ---------------------------------------------------------------------------
__global__ __launch_bounds__(256) void transpose_dl(const bf16* __restrict__ src,
                                                    bf16* __restrict__ dst) {
    __shared__ bf16 ts[32][33];
    const int b = blockIdx.z;
    const int l0 = blockIdx.x * 32, d0 = blockIdx.y * 32;
    const int tid = threadIdx.x;
    const int c = tid & 31, r0 = tid >> 5;
#pragma unroll
    for (int p = 0; p < 4; p++) {
        int r = r0 + p * 8;
        ts[r][c] = src[((size_t)b * DD + d0 + r) * LL + l0 + c];
    }
    __syncthreads();
#pragma unroll
    for (int p = 0; p < 4; p++) {
        int r = r0 + p * 8;
        dst[((size_t)b * LL + l0 + r) * DD + d0 + c] = ts[c][r];
    }
}

// ---------------------------------------------------------------------------
// launch
// ---------------------------------------------------------------------------
extern "C" void kernel_launch(void* const* d_in, const int* in_sizes, int n_in,
                              void* d_out, int out_size, void* d_ws, size_t ws_size,
                              hipStream_t stream) {
    const float* u   = (const float*)d_in[0];
    const float* Wq  = (const float*)d_in[1];
    const float* bq  = (const float*)d_in[2];
    const float* Wk  = (const float*)d_in[3];
    const float* bk  = (const float*)d_in[4];
    const float* Wv  = (const float*)d_in[5];
    const float* bv  = (const float*)d_in[6];
    const float* cqw = (const float*)d_in[7];
    const float* cqb = (const float*)d_in[8];
    const float* ckw = (const float*)d_in[9];
    const float* ckb = (const float*)d_in[10];
    const float* ssm = (const float*)d_in[11];
    const float* Dsk = (const float*)d_in[12];
    const float* Wo  = (const float*)d_in[13];
    const float* bo  = (const float*)d_in[14];

    char* w = (char*)d_ws;
    bf16* u_bf    = (bf16*)(w);                  // 33.55 MB (reused as ygT)
    bf16* Wqkv_bf = (bf16*)(w + 33554432ull);    // 25.2 MB (q|k|v rows concat)
    bf16* Wo_bf   = (bf16*)(w + 58720256ull);    // 8.39 MB
    bf16* qkvT    = (bf16*)(w + 67108864ull);    // 100.7 MB (6144 x 8192)
    bf16* qcT     = (bf16*)(w + 167772160ull);   // 33.55 MB
    bf16* kvT     = (bf16*)(w + 201326592ull);   // 33.55 MB
    // total: 234,881,024 B

    // fp32 -> bf16 conversions (Wq|Wk|Wv into contiguous Wqkv)
    cvt_f32_bf16<<<8192, 256, 0, stream>>>(u, u_bf, MM * DD / 8);
    cvt_f32_bf16<<<2048, 256, 0, stream>>>(Wq, Wqkv_bf, DD * DD / 8);
    cvt_f32_bf16<<<2048, 256, 0, stream>>>(Wk, Wqkv_bf + 4194304, DD * DD / 8);
    cvt_f32_bf16<<<2048, 256, 0, stream>>>(Wv, Wqkv_bf + 8388608, DD * DD / 8);
    cvt_f32_bf16<<<2048, 256, 0, stream>>>(Wo, Wo_bf, DD * DD / 8);

    // fused q/k/v projection -> transposed output (E, B*L); 768 wg, 8 waves
    gemm_qkv<<<(MM / 256) * (NN / 256), 512, 0, stream>>>(u_bf, Wqkv_bf, bq, bk, bv, qkvT);

    // depthwise convs + kv (row-wise on transposed layout)
    dwconv_kv2<<<BB * DD, 256, 0, stream>>>(qkvT, cqw, cqb, ckw, ckb, qcT, kvT);

    // causal long conv (Toeplitz MFMA) + gating
    bf16* ygT = u_bf; // reuse
    longconv_gate<<<DD, 128, 0, stream>>>(kvT, qcT, ssm, Dsk, ygT);

    // transpose back to (B,L,E)
    bf16* ygTT = qkvT; // reuse
    dim3 gc(LL / 32, DD / 32, BB);
    transpose_dl<<<gc, 256, 0, stream>>>(ygT, ygTT);

    // output projection -> fp32 d_out; 256 wg, 8 waves
    gemm_bt_f32<<<(MM / 256) * (DD / 256), 512, 0, stream>>>(ygTT, Wo_bf, bo,
                                                             (float*)d_out, DD, DD);
}

// Round 3
// 578.247 us; speedup vs baseline: 1.1548x; 1.0144x over previous
//
#include <hip/hip_runtime.h>
#include <cstdint>
#include <cstddef>

#define DD 2048
#define LL 2048
#define BB 4
#define MM (BB * LL) // 8192
#define NN 6144      // fused q|k|v output columns

typedef __bf16 bf16;
typedef __bf16 bf16x8 __attribute__((ext_vector_type(8)));
typedef __bf16 bf16x4 __attribute__((ext_vector_type(4)));
typedef __bf16 bf16x2 __attribute__((ext_vector_type(2)));
typedef float f32x4 __attribute__((ext_vector_type(4)));

// ---------------------------------------------------------------------------
// async global -> LDS, 16B per lane (wave-uniform base + lane*16 layout)
// ---------------------------------------------------------------------------
__device__ __forceinline__ void gload16(const void* g, void* l) {
    __builtin_amdgcn_global_load_lds(
        (const __attribute__((address_space(1))) void*)g,
        (__attribute__((address_space(3))) void*)l, 16, 0, 0);
}

// ---------------------------------------------------------------------------
// fp32 -> bf16 conversion (8 elements/thread)
// ---------------------------------------------------------------------------
__global__ __launch_bounds__(256) void cvt_f32_bf16(const float* __restrict__ s,
                                                    bf16* __restrict__ d, int n8) {
    int i = blockIdx.x * 256 + threadIdx.x;
    if (i >= n8) return;
    const float4* sp = (const float4*)s + (size_t)i * 2;
    float4 a = sp[0], b = sp[1];
    bf16x8 o;
    o[0] = (bf16)a.x; o[1] = (bf16)a.y; o[2] = (bf16)a.z; o[3] = (bf16)a.w;
    o[4] = (bf16)b.x; o[5] = (bf16)b.y; o[6] = (bf16)b.z; o[7] = (bf16)b.w;
    *((bf16x8*)d + i) = o;
}

// ---------------------------------------------------------------------------
// 256x256 8-wave deep-pipelined K-loop (BK=64, 2 LDS buffers = 128 KiB).
// 4 phases per K-tile, balanced ds_reads (8/4/8/4), counted vmcnt(4) at
// phases 0/2 (never 0 in main loop), 2 barriers/phase, setprio(1) around
// each 16-MFMA cluster.  Phase split: P0 = h0 x A-rows 0-63 (all 4 B-frags),
// P1 = h0 x A-rows 64-127 (B-frags reused from registers), P2/P3 = same on h1.
// LDS fragment layout XOR-swizzled (slot = fg ^ ((row>>1)&3)) via
// pre-swizzled GLOBAL source addresses + same swizzle on ds_read side.
//
// LDS map (bf16 idx): A0 [0,16384) A1 [16384,32768) B0 [32768,49152) B1 [49152,65536)
// ---------------------------------------------------------------------------
__device__ __forceinline__ void stage_half(const bf16* g, bf16* l, size_t rstep, int tid) {
    gload16(g, l + tid * 8);
    gload16(g + rstep, l + 4096 + tid * 8);
}

#define MFMA_BLK(IOFF)                                                          \
    __builtin_amdgcn_s_setprio(1);                                              \
    _Pragma("unroll") for (int j = 0; j < 4; j++)                               \
        _Pragma("unroll") for (int i = 0; i < 4; i++)                           \
            acc[(IOFF) + i][j] = __builtin_amdgcn_mfma_f32_16x16x32_bf16(       \
                af[i], bq[j], acc[(IOFF) + i][j], 0, 0, 0);                     \
    __builtin_amdgcn_s_setprio(0);

template <int NT>
__device__ __forceinline__ void mma256_loop(const bf16* gA, const bf16* gB,
                                            int Kdim, bf16* lds,
                                            f32x4 (&acc)[8][4]) {
    const int tid = threadIdx.x;
    const int wave = tid >> 6, lane = tid & 63;
    const int wm = wave >> 2, wn = wave & 3;     // 2 x 4 wave grid
    const int fm = lane & 15, fg = lane >> 4;
    const size_t rstep = (size_t)128 * Kdim;
    // per-lane swizzled chunk offset for fragment reads (involution w/ staging)
    const int koff = ((fg ^ ((fm >> 1) & 3)) << 3);
    const int aoff = (wm * 128 + fm) * 32 + koff;
    const int boff = (wn * 64 + fm) * 32 + koff;

    bf16* const A0 = lds;
    bf16* const B0 = lds + 32768;

#pragma unroll
    for (int i = 0; i < 8; i++)
#pragma unroll
        for (int j = 0; j < 4; j++) acc[i][j] = (f32x4){0.f, 0.f, 0.f, 0.f};

    // prologue: stage tile 0 -> buf0 (issue order = consume order)
    stage_half(gA, A0, rstep, tid);
    stage_half(gB, B0, rstep, tid);
    stage_half(gA + 32, A0 + 8192, rstep, tid);
    stage_half(gB + 32, B0 + 8192, rstep, tid);

    bf16x8 af[4], bq[4];

    for (int t = 0; t < NT; ++t) {
        const int c = t & 1;
        bf16* const Ac = A0 + c * 16384;
        bf16* const Bc = B0 + c * 16384;
        bf16* const An = A0 + (c ^ 1) * 16384;
        bf16* const Bn = B0 + (c ^ 1) * 16384;
        const bf16* a1 = gA + (t + 1) * 64;
        const bf16* b1 = gB + (t + 1) * 64;
        const bool st = (t + 1 < NT);

        // ---- P0: h=0, A-rows 0-63, all B ----
        asm volatile("s_waitcnt vmcnt(4)" ::: "memory"); // tile-t h0 resident
        __builtin_amdgcn_s_barrier();
#pragma unroll
        for (int i = 0; i < 4; i++) af[i] = *(const bf16x8*)(Ac + aoff + i * 512);
#pragma unroll
        for (int j = 0; j < 4; j++) bq[j] = *(const bf16x8*)(Bc + boff + j * 512);
        if (st) stage_half(a1, An, rstep, tid); // A-h0 of t+1
        __builtin_amdgcn_s_barrier();
        asm volatile("s_waitcnt lgkmcnt(0)" ::: "memory");
        MFMA_BLK(0)

        // ---- P1: h=0, A-rows 64-127, B reused ----
        __builtin_amdgcn_s_barrier();
#pragma unroll
        for (int i = 0; i < 4; i++) af[i] = *(const bf16x8*)(Ac + aoff + (i + 4) * 512);
        if (st) stage_half(b1, Bn, rstep, tid); // B-h0 of t+1
        __builtin_amdgcn_s_barrier();
        asm volatile("s_waitcnt lgkmcnt(0)" ::: "memory");
        MFMA_BLK(4)

        // ---- P2: h=1, A-rows 0-63, all B ----
        if (st) { asm volatile("s_waitcnt vmcnt(4)" ::: "memory"); } // tile-t h1 resident
        else    { asm volatile("s_waitcnt vmcnt(0)" ::: "memory"); } // last tile: drain
        __builtin_amdgcn_s_barrier();
#pragma unroll
        for (int i = 0; i < 4; i++) af[i] = *(const bf16x8*)(Ac + 8192 + aoff + i * 512);
#pragma unroll
        for (int j = 0; j < 4; j++) bq[j] = *(const bf16x8*)(Bc + 8192 + boff + j * 512);
        if (st) stage_half(a1 + 32, An + 8192, rstep, tid); // A-h1 of t+1
        __builtin_amdgcn_s_barrier();
        asm volatile("s_waitcnt lgkmcnt(0)" ::: "memory");
        MFMA_BLK(0)

        // ---- P3: h=1, A-rows 64-127, B reused ----
        __builtin_amdgcn_s_barrier();
#pragma unroll
        for (int i = 0; i < 4; i++) af[i] = *(const bf16x8*)(Ac + 8192 + aoff + (i + 4) * 512);
        if (st) stage_half(b1 + 32, Bn + 8192, rstep, tid); // B-h1 of t+1
        __builtin_amdgcn_s_barrier();
        asm volatile("s_waitcnt lgkmcnt(0)" ::: "memory");
        MFMA_BLK(4)
    }
}

// ---------------------------------------------------------------------------
// Fused QKV GEMM: C[m,n] = sum_k A[m,k]*Wqkv[n,k] + bias(n), written
// TRANSPOSED: out[n][m] (bf16, (6144, 8192)).  256x256 tile, 8-phase pipe.
// L2-aware block mapping: XCD x owns m-blocks [4x,4x+4) x ALL 24 n-blocks
// (m-fast within groups of 4) -> resident window per XCD = 4m x 8n ->
// A-resident 4 MB (fits 4 MiB L2), per-K-slice working set ~384 KB.
// ---------------------------------------------------------------------------
__global__ __launch_bounds__(512, 2) void gemm_qkv(const bf16* __restrict__ A,
                                                   const bf16* __restrict__ Bm,
                                                   const float* __restrict__ bqp,
                                                   const float* __restrict__ bkp,
                                                   const float* __restrict__ bvp,
                                                   bf16* __restrict__ CtOut) {
    __shared__ bf16 lds[65536]; // 128 KiB: A/B double buffers, then C-stage
    const int id = blockIdx.x;        // nwg = 768 = 8 XCD x (4m x 24n)
    const int xcd = id & 7, li = id >> 3;
    const int m0 = (xcd * 4 + (li & 3)) << 8;  // 32 m-blocks
    const int n0 = (li >> 2) << 8;             // 24 n-blocks

    const int tid = threadIdx.x;
    const int wave = tid >> 6, lane = tid & 63;
    // staging source (pre-swizzled global address; LDS dest stays linear)
    const int srow = tid >> 2;                                   // 0..127
    const int skx = (((lane & 3) ^ ((lane >> 3) & 3)) << 3);     // swizzled chunk
    const bf16* gA = A + (size_t)(m0 + srow) * DD + skx;
    const bf16* gB = Bm + (size_t)(n0 + srow) * DD + skx;

    f32x4 acc[8][4];
    mma256_loop<DD / 64>(gA, gB, DD, lds, acc);

    // ---- epilogue: bias + transposed store via swizzled LDS C-stage ----
    __syncthreads(); // loop fully drained; safe to reuse LDS
    const int wm = wave >> 2, wn = wave & 3;
    const int fm = lane & 15, fg = lane >> 4;
    const float* bp = (n0 < 2048) ? bqp : ((n0 < 4096) ? bkp : bvp);
    const int nb = n0 & 2047;
#pragma unroll
    for (int j = 0; j < 4; j++) {
        const int col = wn * 64 + j * 16 + fm;
        const float bvv = bp[nb + col];
        const int csw = (col & 7) << 3;
#pragma unroll
        for (int i = 0; i < 8; i++) {
            const int row = (wm * 128 + i * 16 + fg * 4) ^ csw; // bits>=3 only
            bf16x4 o;
#pragma unroll
            for (int r = 0; r < 4; r++) o[r] = (bf16)(acc[i][j][r] + bvv);
            *(bf16x4*)&lds[col * 256 + row] = o;
        }
    }
    __syncthreads();
    const int ccol = tid >> 5, chunk = tid & 31;
#pragma unroll
    for (int p = 0; p < 16; p++) {
        const int col = p * 16 + ccol;
        bf16x8 vv = *(const bf16x8*)&lds[col * 256 + ((chunk * 8) ^ ((col & 7) << 3))];
        *(bf16x8*)(CtOut + (size_t)(n0 + col) * MM + m0 + chunk * 8) = vv;
    }
}

// ---------------------------------------------------------------------------
// Output projection GEMM (row-major f32 out): C[m,n] = sum_k A[m,k]*B[n,k]+b[n]
// Same 256x256 pipeline + L2-aware mapping (nwg = 256 = 8 XCD x (4m x 8n)).
// ---------------------------------------------------------------------------
__global__ __launch_bounds__(512, 2) void gemm_bt_f32(const bf16* __restrict__ A,
                                                      const bf16* __restrict__ Bm,
                                                      const float* __restrict__ bias,
                                                      float* __restrict__ C,
                                                      int Ndim, int Kdim) {
    __shared__ bf16 lds[65536];
    const int id = blockIdx.x;
    const int xcd = id & 7, li = id >> 3;
    const int m0 = (xcd * 4 + (li & 3)) << 8;  // 32 m-blocks
    const int n0 = (li >> 2) << 8;             // 8 n-blocks

    const int tid = threadIdx.x;
    const int wave = tid >> 6, lane = tid & 63;
    const int srow = tid >> 2;
    const int skx = (((lane & 3) ^ ((lane >> 3) & 3)) << 3);
    const bf16* gA = A + (size_t)(m0 + srow) * Kdim + skx;
    const bf16* gB = Bm + (size_t)(n0 + srow) * Kdim + skx;

    f32x4 acc[8][4];
    mma256_loop<DD / 64>(gA, gB, Kdim, lds, acc);

    const int wm = wave >> 2, wn = wave & 3;
    const int fm = lane & 15, fg = lane >> 4;
#pragma unroll
    for (int j = 0; j < 4; j++) {
        const int col = n0 + wn * 64 + j * 16 + fm;
        const float bvv = bias[col];
#pragma unroll
        for (int i = 0; i < 8; i++) {
#pragma unroll
            for (int r = 0; r < 4; r++) {
                const int row = m0 + wm * 128 + i * 16 + fg * 4 + r;
                C[(size_t)row * Ndim + col] = acc[i][j][r] + bvv;
            }
        }
    }
}

// ---------------------------------------------------------------------------
// Depthwise causal conv (width 3) on qT/kT rows + kv=conv(k)*v.  (unchanged)
// ---------------------------------------------------------------------------
__global__ __launch_bounds__(256) void dwconv_kv2(
    const bf16* __restrict__ qkvT,
    const float* __restrict__ cqw, const float* __restrict__ cqb,
    const float* __restrict__ ckw, const float* __restrict__ ckb,
    bf16* __restrict__ qcT, bf16* __restrict__ kvT) {
    const int bid = blockIdx.x;
    const int b = bid >> 11, d = bid & (DD - 1);
    const int tid = threadIdx.x;
    const int l = tid * 8;

    const bf16* qR = qkvT + (size_t)d * MM + b * LL;
    const bf16* kR = qkvT + (size_t)(2048 + d) * MM + b * LL;
    const bf16* vR = qkvT + (size_t)(4096 + d) * MM + b * LL;

    const float q0 = cqw[d * 3], q1 = cqw[d * 3 + 1], q2 = cqw[d * 3 + 2];
    const float k0 = ckw[d * 3], k1 = ckw[d * 3 + 1], k2 = ckw[d * 3 + 2];
    const float qb = cqb[d], kb = ckb[d];

    bf16x8 qx = *(const bf16x8*)(qR + l);
    bf16x8 kx = *(const bf16x8*)(kR + l);
    bf16x8 vx = *(const bf16x8*)(vR + l);

    float xq[10], xk[10];
    xq[0] = 0.f; xq[1] = 0.f; xk[0] = 0.f; xk[1] = 0.f;
    if (l >= 2) {
        bf16x2 qh = *(const bf16x2*)(qR + l - 2);
        bf16x2 kh = *(const bf16x2*)(kR + l - 2);
        xq[0] = (float)qh[0]; xq[1] = (float)qh[1];
        xk[0] = (float)kh[0]; xk[1] = (float)kh[1];
    }
#pragma unroll
    for (int c = 0; c < 8; c++) { xq[c + 2] = (float)qx[c]; xk[c + 2] = (float)kx[c]; }

    bf16x8 oq, okv;
#pragma unroll
    for (int c = 0; c < 8; c++) {
        float qc = q0 * xq[c] + q1 * xq[c + 1] + q2 * xq[c + 2] + qb;
        float kc = k0 * xk[c] + k1 * xk[c + 1] + k2 * xk[c + 2] + kb;
        oq[c] = (bf16)qc;
        okv[c] = (bf16)(kc * (float)vx[c]);
    }
    const size_t o = ((size_t)b * DD + d) * LL + l;
    *(bf16x8*)(qcT + o) = oq;
    *(bf16x8*)(kvT + o) = okv;
}

// ---------------------------------------------------------------------------
// Causal long conv + D-skip + q gating via Toeplitz MFMA.  (unchanged)
// ---------------------------------------------------------------------------
__global__ __launch_bounds__(128, 2) void longconv_gate(
    const bf16* __restrict__ kvT, const bf16* __restrict__ qcT,
    const float* __restrict__ kern, const float* __restrict__ Dskip,
    bf16* __restrict__ ygT) {
    __shared__ bf16 kv_ls[4 * 2112];
    __shared__ float krev_f[2112];
    const int d = blockIdx.x;
    const int tid = threadIdx.x;

    {
        const int bb = tid >> 5, t32 = tid & 31;
#pragma unroll
        for (int c = 0; c < 8; ++c) {
            const int l = (c * 32 + t32) * 8;
            bf16x8 v = *(const bf16x8*)(kvT + ((size_t)bb * DD + d) * LL + l);
            *(bf16x8*)&kv_ls[2112 * bb + 48 + l] = v;
        }
        if (tid < 48) {
#pragma unroll
            for (int b2 = 0; b2 < 4; b2++) kv_ls[2112 * b2 + tid] = (bf16)0.f;
        } else if (tid < 64) {
#pragma unroll
            for (int b2 = 0; b2 < 4; b2++) kv_ls[2112 * b2 + 2048 + tid] = (bf16)0.f;
        }
    }
    {
        const float* kr = kern + (size_t)d * LL;
#pragma unroll
        for (int c = 0; c < 16; ++c) {
            const int x = c * 128 + tid;
            krev_f[x] = kr[2047 - x];
        }
        if (tid < 64) krev_f[2048 + tid] = 0.f;
    }
    __syncthreads();

    const int lane = tid & 63;
    const int w = __builtin_amdgcn_readfirstlane(tid >> 6);
    const int n = lane & 15, q = lane >> 4;
    const int b = n & 3, pp = n >> 2;
    const int cB = 2112 * b + 16 * pp + 8 * q;

    f32x4 acc[16];
#pragma unroll
    for (int s = 0; s < 16; s++) acc[s] = (f32x4){0.f, 0.f, 0.f, 0.f};

    for (int it = 0; it < 64; ++it) {
        const int as = 2031 - 32 * it - n + 8 * q;
        float af[8];
#pragma unroll
        for (int j = 0; j < 8; j++) af[j] = krev_f[as + j];
        bf16x8 a;
#pragma unroll
        for (int j = 0; j < 8; j++) a[j] = (bf16)af[j];

        const int bbase = cB + 64 * w + 32 - 32 * it;
#pragma unroll
        for (int h = 0; h < 2; ++h) {
            bf16x8 bfr[8];
#pragma unroll
            for (int s8 = 0; s8 < 8; s8++) {
                const int s = h * 8 + s8;
                if (it <= 4 * s + 2 * w + 1)
                    bfr[s8] = *(const bf16x8*)&kv_ls[bbase + 128 * s];
            }
#pragma unroll
            for (int s8 = 0; s8 < 8; s8++) {
                const int s = h * 8 + s8;
                if (it <= 4 * s + 2 * w + 1)
                    acc[s] = __builtin_amdgcn_mfma_f32_16x16x32_bf16(
                        a, bfr[s8], acc[s], 0, 0, 0);
            }
        }
    }

    const float dsk = Dskip[d];
#pragma unroll
    for (int s = 0; s < 16; s++) {
        const int i = 2 * s + w;
        const int l = 64 * i + 16 * pp + 4 * q;
        const size_t gb = ((size_t)b * DD + d) * LL + l;
        bf16x4 qc4 = *(const bf16x4*)&qcT[gb];
        bf16x4 kv4 = *(const bf16x4*)&kv_ls[2112 * b + 48 + l];
        bf16x4 o;
#pragma unroll
        for (int r = 0; r < 4; r++) {
            float val = (acc[s][r] + (float)kv4[r] * dsk) * (float)qc4[r];
            o[r] = (bf16)val;
        }
        *(bf16x4*)&ygT[gb] = o;
    }
}

// ---------------------------------------------------------------------------
// bf16 transpose (B, D, L) -> (B, L, D), 64x64 tiles, fully vectorized:
// bf16x8 global loads (2 rows/thread -> full 64-row tile), XOR-swizzled LDS
// (conflict-free b128 writes, 2-way scalar reads = free), bf16x8 stores.
// ---------------------------------------------------------------------------
__global__ __launch_bounds__(256) void transpose_dl(const bf16* __restrict__ src,
                                                    bf16* __restrict__ dst) {
    __shared__ bf16 ts[64 * 64]; // 8 KB, row r holds d0+r, l-chunks XOR-swizzled
    const int b = blockIdx.z;
    const int l0 = blockIdx.x * 64, d0 = blockIdx.y * 64;
    const int tid = threadIdx.x;
    {
        const int r0 = tid >> 3, c8 = tid & 7; // row = d, 8 l-chunks of 8
#pragma unroll
        for (int h = 0; h < 2; h++) {
            const int r = r0 + h * 32;
            bf16x8 v = *(const bf16x8*)&src[((size_t)b * DD + d0 + r) * LL + l0 + c8 * 8];
            *(bf16x8*)&ts[r * 64 + ((c8 ^ (r & 7)) << 3)] = v;
        }
    }
    __syncthreads();
    const int l = tid & 63, dc0 = (tid >> 6) << 3;
#pragma unroll
    for (int half = 0; half < 2; half++) {
        const int dc = dc0 + half * 32;
        bf16x8 o;
#pragma unroll
        for (int j = 0; j < 8; j++) {
            const int r = dc + j;
            o[j] = ts[r * 64 + (((l >> 3) ^ (r & 7)) << 3) + (l & 7)];
        }
        *(bf16x8*)&dst[((size_t)b * LL + l0 + l) * DD + d0 + dc] = o;
    }
}

// ---------------------------------------------------------------------------
// launch
// ---------------------------------------------------------------------------
extern "C" void kernel_launch(void* const* d_in, const int* in_sizes, int n_in,
                              void* d_out, int out_size, void* d_ws, size_t ws_size,
                              hipStream_t stream) {
    const float* u   = (const float*)d_in[0];
    const float* Wq  = (const float*)d_in[1];
    const float* bq  = (const float*)d_in[2];
    const float* Wk  = (const float*)d_in[3];
    const float* bk  = (const float*)d_in[4];
    const float* Wv  = (const float*)d_in[5];
    const float* bv  = (const float*)d_in[6];
    const float* cqw = (const float*)d_in[7];
    const float* cqb = (const float*)d_in[8];
    const float* ckw = (const float*)d_in[9];
    const float* ckb = (const float*)d_in[10];
    const float* ssm = (const float*)d_in[11];
    const float* Dsk = (const float*)d_in[12];
    const float* Wo  = (const float*)d_in[13];
    const float* bo  = (const float*)d_in[14];

    char* w = (char*)d_ws;
    bf16* u_bf    = (bf16*)(w);                  // 33.55 MB (reused as ygT)
    bf16* Wqkv_bf = (bf16*)(w + 33554432ull);    // 25.2 MB (q|k|v rows concat)
    bf16* Wo_bf   = (bf16*)(w + 58720256ull);    // 8.39 MB
    bf16* qkvT    = (bf16*)(w + 67108864ull);    // 100.7 MB (6144 x 8192)
    bf16* qcT     = (bf16*)(w + 167772160ull);   // 33.55 MB
    bf16* kvT     = (bf16*)(w + 201326592ull);   // 33.55 MB
    // total: 234,881,024 B

    // fp32 -> bf16 conversions (Wq|Wk|Wv into contiguous Wqkv)
    cvt_f32_bf16<<<8192, 256, 0, stream>>>(u, u_bf, MM * DD / 8);
    cvt_f32_bf16<<<2048, 256, 0, stream>>>(Wq, Wqkv_bf, DD * DD / 8);
    cvt_f32_bf16<<<2048, 256, 0, stream>>>(Wk, Wqkv_bf + 4194304, DD * DD / 8);
    cvt_f32_bf16<<<2048, 256, 0, stream>>>(Wv, Wqkv_bf + 8388608, DD * DD / 8);
    cvt_f32_bf16<<<2048, 256, 0, stream>>>(Wo, Wo_bf, DD * DD / 8);

    // fused q/k/v projection -> transposed output (E, B*L); 768 wg, 8 waves
    gemm_qkv<<<(MM / 256) * (NN / 256), 512, 0, stream>>>(u_bf, Wqkv_bf, bq, bk, bv, qkvT);

    // depthwise convs + kv (row-wise on transposed layout)
    dwconv_kv2<<<BB * DD, 256, 0, stream>>>(qkvT, cqw, cqb, ckw, ckb, qcT, kvT);

    // causal long conv (Toeplitz MFMA) + gating
    bf16* ygT = u_bf; // reuse
    longconv_gate<<<DD, 128, 0, stream>>>(kvT, qcT, ssm, Dsk, ygT);

    // transpose back to (B,L,E)
    bf16* ygTT = qkvT; // reuse
    dim3 gc(LL / 64, DD / 64, BB);
    transpose_dl<<<gc, 256, 0, stream>>>(ygT, ygTT);

    // output projection -> fp32 d_out; 256 wg, 8 waves
    gemm_bt_f32<<<(MM / 256) * (DD / 256), 512, 0, stream>>>(ygTT, Wo_bf, bo,
                                                             (float*)d_out, DD, DD);
}

// Round 4
// 568.135 us; speedup vs baseline: 1.1754x; 1.0178x over previous
//
#include <hip/hip_runtime.h>
#include <cstdint>
#include <cstddef>

#define DD 2048
#define LL 2048
#define BB 4
#define MM (BB * LL) // 8192
#define NN 6144      // fused q|k|v output columns

typedef __bf16 bf16;
typedef __bf16 bf16x8 __attribute__((ext_vector_type(8)));
typedef __bf16 bf16x4 __attribute__((ext_vector_type(4)));
typedef __bf16 bf16x2 __attribute__((ext_vector_type(2)));
typedef float f32x4 __attribute__((ext_vector_type(4)));

// ---------------------------------------------------------------------------
// async global -> LDS, 16B per lane (wave-uniform base + lane*16 layout)
// ---------------------------------------------------------------------------
__device__ __forceinline__ void gload16(const void* g, void* l) {
    __builtin_amdgcn_global_load_lds(
        (const __attribute__((address_space(1))) void*)g,
        (__attribute__((address_space(3))) void*)l, 16, 0, 0);
}

// ---------------------------------------------------------------------------
// fused fp32 -> bf16 conversion for all 5 tensors (1 launch instead of 5).
// blocks [0,8192): u; [8192,10240): Wq; [10240,12288): Wk; [12288,14336): Wv;
// [14336,16384): Wo.  8 elems/thread.
// ---------------------------------------------------------------------------
__global__ __launch_bounds__(256) void cvt_all(
    const float* __restrict__ u, const float* __restrict__ wq,
    const float* __restrict__ wk, const float* __restrict__ wv,
    const float* __restrict__ wo, bf16* __restrict__ u_bf,
    bf16* __restrict__ wqkv, bf16* __restrict__ wo_bf) {
    const int blk = blockIdx.x;
    const float* s;
    bf16* d;
    int base;
    if (blk < 8192)       { s = u;  d = u_bf;            base = 0; }
    else if (blk < 10240) { s = wq; d = wqkv;            base = 8192; }
    else if (blk < 12288) { s = wk; d = wqkv + 4194304;  base = 10240; }
    else if (blk < 14336) { s = wv; d = wqkv + 8388608;  base = 12288; }
    else                  { s = wo; d = wo_bf;           base = 14336; }
    const int i = (blk - base) * 256 + threadIdx.x;
    const float4* sp = (const float4*)s + (size_t)i * 2;
    float4 a = sp[0], b = sp[1];
    bf16x8 o;
    o[0] = (bf16)a.x; o[1] = (bf16)a.y; o[2] = (bf16)a.z; o[3] = (bf16)a.w;
    o[4] = (bf16)b.x; o[5] = (bf16)b.y; o[6] = (bf16)b.z; o[7] = (bf16)b.w;
    *((bf16x8*)d + i) = o;
}

// ---------------------------------------------------------------------------
// 256x256 8-wave K-loop (BK=64, 2 LDS buffers = 128 KiB), within-tile
// register read-ahead: only 2 barriers per K-tile (h0/h1 residency gates),
// counted vmcnt(4) (never 0 until last tile), and counted lgkm waits left to
// the compiler (all ds_reads are C++ loads -> dependence-exact lgkmcnt(N)).
// Per tile: [vmcnt4;bar] R0(8)+stageAh0+R1(4); MFMA(R0) overlaps R1 xfer;
// stageBh0; [vmcnt4;bar] R2(8)+stageAh1; MFMA(R1) overlaps R2; R3(4)+stageBh1;
// MFMA(R2) overlaps R3; MFMA(R3).  LDS frag layout XOR-swizzled
// (chunk = fg ^ ((row>>1)&3)) via pre-swizzled GLOBAL source + same swizzle
// on the ds_read side (dense 1KB per wave-read -> conflict-free).
//
// LDS map (bf16 idx): A0 [0,16384) A1 [16384,32768) B0 [32768,49152) B1 [49152,65536)
// ---------------------------------------------------------------------------
__device__ __forceinline__ void stage_half(const bf16* g, bf16* l, size_t rstep, int tid) {
    gload16(g, l + tid * 8);
    gload16(g + rstep, l + 4096 + tid * 8);
}

#define MFMA_BLK(AF, BQ, IOFF)                                                  \
    __builtin_amdgcn_s_setprio(1);                                              \
    _Pragma("unroll") for (int j = 0; j < 4; j++)                               \
        _Pragma("unroll") for (int i = 0; i < 4; i++)                           \
            acc[(IOFF) + i][j] = __builtin_amdgcn_mfma_f32_16x16x32_bf16(       \
                AF[i], BQ[j], acc[(IOFF) + i][j], 0, 0, 0);                     \
    __builtin_amdgcn_s_setprio(0);

template <int NT>
__device__ __forceinline__ void mma256_loop(const bf16* gA, const bf16* gB,
                                            int Kdim, bf16* lds,
                                            f32x4 (&acc)[8][4]) {
    const int tid = threadIdx.x;
    const int wave = tid >> 6, lane = tid & 63;
    const int wm = wave >> 2, wn = wave & 3;     // 2 x 4 wave grid
    const int fm = lane & 15, fg = lane >> 4;
    const size_t rstep = (size_t)128 * Kdim;
    // per-lane swizzled chunk offset for fragment reads (involution w/ staging)
    const int koff = ((fg ^ ((fm >> 1) & 3)) << 3);
    const int aoff = (wm * 128 + fm) * 32 + koff;
    const int boff = (wn * 64 + fm) * 32 + koff;

    bf16* const A0 = lds;
    bf16* const B0 = lds + 32768;

#pragma unroll
    for (int i = 0; i < 8; i++)
#pragma unroll
        for (int j = 0; j < 4; j++) acc[i][j] = (f32x4){0.f, 0.f, 0.f, 0.f};

    // prologue: stage tile 0 -> buf0 (issue order = consume order)
    stage_half(gA, A0, rstep, tid);
    stage_half(gB, B0, rstep, tid);
    stage_half(gA + 32, A0 + 8192, rstep, tid);
    stage_half(gB + 32, B0 + 8192, rstep, tid);

    bf16x8 af0[4], af1[4], bq0[4], bq1[4];

    for (int t = 0; t < NT; ++t) {
        const int c = t & 1;
        bf16* const Ac = A0 + c * 16384;
        bf16* const Bc = B0 + c * 16384;
        bf16* const An = A0 + (c ^ 1) * 16384;
        bf16* const Bn = B0 + (c ^ 1) * 16384;
        const bf16* a1 = gA + (t + 1) * 64;
        const bf16* b1 = gB + (t + 1) * 64;
        const bool st = (t + 1 < NT);

        // ---- h0 residency gate (tile-t h0 landed chip-wide) ----
        asm volatile("s_waitcnt vmcnt(4)" ::: "memory");
        asm volatile("s_barrier" ::: "memory");
        // R0: A h0 rows 0-63 + B h0 (8 reads)
#pragma unroll
        for (int i = 0; i < 4; i++) af0[i] = *(const bf16x8*)(Ac + aoff + i * 512);
#pragma unroll
        for (int j = 0; j < 4; j++) bq0[j] = *(const bf16x8*)(Bc + boff + j * 512);
        if (st) stage_half(a1, An, rstep, tid); // A-h0 of t+1 -> buf c^1
        // R1: A h0 rows 64-127 (4 reads, stays in flight during MFMA(R0))
#pragma unroll
        for (int i = 0; i < 4; i++) af1[i] = *(const bf16x8*)(Ac + aoff + (i + 4) * 512);
        MFMA_BLK(af0, bq0, 0)                   // compiler waits lgkm for R0 only
        if (st) stage_half(b1, Bn, rstep, tid); // B-h0 of t+1

        // ---- h1 residency gate ----
        if (st) { asm volatile("s_waitcnt vmcnt(4)" ::: "memory"); }
        else    { asm volatile("s_waitcnt vmcnt(0)" ::: "memory"); }
        asm volatile("s_barrier" ::: "memory");
        // R2: A h1 rows 0-63 + B h1 (8 reads; reuse af0 regs)
#pragma unroll
        for (int i = 0; i < 4; i++) af0[i] = *(const bf16x8*)(Ac + 8192 + aoff + i * 512);
#pragma unroll
        for (int j = 0; j < 4; j++) bq1[j] = *(const bf16x8*)(Bc + 8192 + boff + j * 512);
        if (st) stage_half(a1 + 32, An + 8192, rstep, tid); // A-h1 of t+1
        MFMA_BLK(af1, bq0, 4)                   // h0 rows 64-127; overlaps R2 xfer
        // R3: A h1 rows 64-127 (reuse af1 regs)
#pragma unroll
        for (int i = 0; i < 4; i++) af1[i] = *(const bf16x8*)(Ac + 8192 + aoff + (i + 4) * 512);
        if (st) stage_half(b1 + 32, Bn + 8192, rstep, tid); // B-h1 of t+1
        MFMA_BLK(af0, bq1, 0)                   // h1 rows 0-63; overlaps R3 xfer
        MFMA_BLK(af1, bq1, 4)                   // h1 rows 64-127
    }
}

// ---------------------------------------------------------------------------
// Fused QKV GEMM: C[m,n] = sum_k A[m,k]*Wqkv[n,k] + bias(n), written
// TRANSPOSED: out[n][m] (bf16, (6144, 8192)).  256x256 tile.
// L2-aware block mapping: XCD x owns m-blocks [4x,4x+4) x ALL 24 n-blocks
// (m-fast within groups of 4).
// ---------------------------------------------------------------------------
__global__ __launch_bounds__(512, 2) void gemm_qkv(const bf16* __restrict__ A,
                                                   const bf16* __restrict__ Bm,
                                                   const float* __restrict__ bqp,
                                                   const float* __restrict__ bkp,
                                                   const float* __restrict__ bvp,
                                                   bf16* __restrict__ CtOut) {
    __shared__ bf16 lds[65536]; // 128 KiB: A/B double buffers, then C-stage
    const int id = blockIdx.x;        // nwg = 768 = 8 XCD x (4m x 24n)
    const int xcd = id & 7, li = id >> 3;
    const int m0 = (xcd * 4 + (li & 3)) << 8;  // 32 m-blocks
    const int n0 = (li >> 2) << 8;             // 24 n-blocks

    const int tid = threadIdx.x;
    const int wave = tid >> 6, lane = tid & 63;
    // staging source (pre-swizzled global address; LDS dest stays linear)
    const int srow = tid >> 2;                                   // 0..127
    const int skx = (((lane & 3) ^ ((lane >> 3) & 3)) << 3);     // swizzled chunk
    const bf16* gA = A + (size_t)(m0 + srow) * DD + skx;
    const bf16* gB = Bm + (size_t)(n0 + srow) * DD + skx;

    f32x4 acc[8][4];
    mma256_loop<DD / 64>(gA, gB, DD, lds, acc);

    // ---- epilogue: bias + transposed store via swizzled LDS C-stage ----
    __syncthreads(); // loop fully drained; safe to reuse LDS
    const int wm = wave >> 2, wn = wave & 3;
    const int fm = lane & 15, fg = lane >> 4;
    const float* bp = (n0 < 2048) ? bqp : ((n0 < 4096) ? bkp : bvp);
    const int nb = n0 & 2047;
#pragma unroll
    for (int j = 0; j < 4; j++) {
        const int col = wn * 64 + j * 16 + fm;
        const float bvv = bp[nb + col];
        const int csw = (col & 7) << 3;
#pragma unroll
        for (int i = 0; i < 8; i++) {
            const int row = (wm * 128 + i * 16 + fg * 4) ^ csw; // bits>=3 only
            bf16x4 o;
#pragma unroll
            for (int r = 0; r < 4; r++) o[r] = (bf16)(acc[i][j][r] + bvv);
            *(bf16x4*)&lds[col * 256 + row] = o;
        }
    }
    __syncthreads();
    const int ccol = tid >> 5, chunk = tid & 31;
#pragma unroll
    for (int p = 0; p < 16; p++) {
        const int col = p * 16 + ccol;
        bf16x8 vv = *(const bf16x8*)&lds[col * 256 + ((chunk * 8) ^ ((col & 7) << 3))];
        *(bf16x8*)(CtOut + (size_t)(n0 + col) * MM + m0 + chunk * 8) = vv;
    }
}

// ---------------------------------------------------------------------------
// Output projection GEMM (row-major f32 out): C[m,n] = sum_k A[m,k]*B[n,k]+b[n]
// Same 256x256 pipeline + L2-aware mapping (nwg = 256 = 8 XCD x (4m x 8n)).
// ---------------------------------------------------------------------------
__global__ __launch_bounds__(512, 2) void gemm_bt_f32(const bf16* __restrict__ A,
                                                      const bf16* __restrict__ Bm,
                                                      const float* __restrict__ bias,
                                                      float* __restrict__ C,
                                                      int Ndim, int Kdim) {
    __shared__ bf16 lds[65536];
    const int id = blockIdx.x;
    const int xcd = id & 7, li = id >> 3;
    const int m0 = (xcd * 4 + (li & 3)) << 8;  // 32 m-blocks
    const int n0 = (li >> 2) << 8;             // 8 n-blocks

    const int tid = threadIdx.x;
    const int wave = tid >> 6, lane = tid & 63;
    const int srow = tid >> 2;
    const int skx = (((lane & 3) ^ ((lane >> 3) & 3)) << 3);
    const bf16* gA = A + (size_t)(m0 + srow) * Kdim + skx;
    const bf16* gB = Bm + (size_t)(n0 + srow) * Kdim + skx;

    f32x4 acc[8][4];
    mma256_loop<DD / 64>(gA, gB, Kdim, lds, acc);

    const int wm = wave >> 2, wn = wave & 3;
    const int fm = lane & 15, fg = lane >> 4;
#pragma unroll
    for (int j = 0; j < 4; j++) {
        const int col = n0 + wn * 64 + j * 16 + fm;
        const float bvv = bias[col];
#pragma unroll
        for (int i = 0; i < 8; i++) {
#pragma unroll
            for (int r = 0; r < 4; r++) {
                const int row = m0 + wm * 128 + i * 16 + fg * 4 + r;
                C[(size_t)row * Ndim + col] = acc[i][j][r] + bvv;
            }
        }
    }
}

// ---------------------------------------------------------------------------
// Depthwise causal conv (width 3) on qT/kT rows + kv=conv(k)*v.  (unchanged)
// ---------------------------------------------------------------------------
__global__ __launch_bounds__(256) void dwconv_kv2(
    const bf16* __restrict__ qkvT,
    const float* __restrict__ cqw, const float* __restrict__ cqb,
    const float* __restrict__ ckw, const float* __restrict__ ckb,
    bf16* __restrict__ qcT, bf16* __restrict__ kvT) {
    const int bid = blockIdx.x;
    const int b = bid >> 11, d = bid & (DD - 1);
    const int tid = threadIdx.x;
    const int l = tid * 8;

    const bf16* qR = qkvT + (size_t)d * MM + b * LL;
    const bf16* kR = qkvT + (size_t)(2048 + d) * MM + b * LL;
    const bf16* vR = qkvT + (size_t)(4096 + d) * MM + b * LL;

    const float q0 = cqw[d * 3], q1 = cqw[d * 3 + 1], q2 = cqw[d * 3 + 2];
    const float k0 = ckw[d * 3], k1 = ckw[d * 3 + 1], k2 = ckw[d * 3 + 2];
    const float qb = cqb[d], kb = ckb[d];

    bf16x8 qx = *(const bf16x8*)(qR + l);
    bf16x8 kx = *(const bf16x8*)(kR + l);
    bf16x8 vx = *(const bf16x8*)(vR + l);

    float xq[10], xk[10];
    xq[0] = 0.f; xq[1] = 0.f; xk[0] = 0.f; xk[1] = 0.f;
    if (l >= 2) {
        bf16x2 qh = *(const bf16x2*)(qR + l - 2);
        bf16x2 kh = *(const bf16x2*)(kR + l - 2);
        xq[0] = (float)qh[0]; xq[1] = (float)qh[1];
        xk[0] = (float)kh[0]; xk[1] = (float)kh[1];
    }
#pragma unroll
    for (int c = 0; c < 8; c++) { xq[c + 2] = (float)qx[c]; xk[c + 2] = (float)kx[c]; }

    bf16x8 oq, okv;
#pragma unroll
    for (int c = 0; c < 8; c++) {
        float qc = q0 * xq[c] + q1 * xq[c + 1] + q2 * xq[c + 2] + qb;
        float kc = k0 * xk[c] + k1 * xk[c + 1] + k2 * xk[c + 2] + kb;
        oq[c] = (bf16)qc;
        okv[c] = (bf16)(kc * (float)vx[c]);
    }
    const size_t o = ((size_t)b * DD + d) * LL + l;
    *(bf16x8*)(qcT + o) = oq;
    *(bf16x8*)(kvT + o) = okv;
}

// ---------------------------------------------------------------------------
// Causal long conv + D-skip + q gating via Toeplitz MFMA.  (unchanged)
// ---------------------------------------------------------------------------
__global__ __launch_bounds__(128, 2) void longconv_gate(
    const bf16* __restrict__ kvT, const bf16* __restrict__ qcT,
    const float* __restrict__ kern, const float* __restrict__ Dskip,
    bf16* __restrict__ ygT) {
    __shared__ bf16 kv_ls[4 * 2112];
    __shared__ float krev_f[2112];
    const int d = blockIdx.x;
    const int tid = threadIdx.x;

    {
        const int bb = tid >> 5, t32 = tid & 31;
#pragma unroll
        for (int c = 0; c < 8; ++c) {
            const int l = (c * 32 + t32) * 8;
            bf16x8 v = *(const bf16x8*)(kvT + ((size_t)bb * DD + d) * LL + l);
            *(bf16x8*)&kv_ls[2112 * bb + 48 + l] = v;
        }
        if (tid < 48) {
#pragma unroll
            for (int b2 = 0; b2 < 4; b2++) kv_ls[2112 * b2 + tid] = (bf16)0.f;
        } else if (tid < 64) {
#pragma unroll
            for (int b2 = 0; b2 < 4; b2++) kv_ls[2112 * b2 + 2048 + tid] = (bf16)0.f;
        }
    }
    {
        const float* kr = kern + (size_t)d * LL;
#pragma unroll
        for (int c = 0; c < 16; ++c) {
            const int x = c * 128 + tid;
            krev_f[x] = kr[2047 - x];
        }
        if (tid < 64) krev_f[2048 + tid] = 0.f;
    }
    __syncthreads();

    const int lane = tid & 63;
    const int w = __builtin_amdgcn_readfirstlane(tid >> 6);
    const int n = lane & 15, q = lane >> 4;
    const int b = n & 3, pp = n >> 2;
    const int cB = 2112 * b + 16 * pp + 8 * q;

    f32x4 acc[16];
#pragma unroll
    for (int s = 0; s < 16; s++) acc[s] = (f32x4){0.f, 0.f, 0.f, 0.f};

    for (int it = 0; it < 64; ++it) {
        const int as = 2031 - 32 * it - n + 8 * q;
        float af[8];
#pragma unroll
        for (int j = 0; j < 8; j++) af[j] = krev_f[as + j];
        bf16x8 a;
#pragma unroll
        for (int j = 0; j < 8; j++) a[j] = (bf16)af[j];

        const int bbase = cB + 64 * w + 32 - 32 * it;
#pragma unroll
        for (int h = 0; h < 2; ++h) {
            bf16x8 bfr[8];
#pragma unroll
            for (int s8 = 0; s8 < 8; s8++) {
                const int s = h * 8 + s8;
                if (it <= 4 * s + 2 * w + 1)
                    bfr[s8] = *(const bf16x8*)&kv_ls[bbase + 128 * s];
            }
#pragma unroll
            for (int s8 = 0; s8 < 8; s8++) {
                const int s = h * 8 + s8;
                if (it <= 4 * s + 2 * w + 1)
                    acc[s] = __builtin_amdgcn_mfma_f32_16x16x32_bf16(
                        a, bfr[s8], acc[s], 0, 0, 0);
            }
        }
    }

    const float dsk = Dskip[d];
#pragma unroll
    for (int s = 0; s < 16; s++) {
        const int i = 2 * s + w;
        const int l = 64 * i + 16 * pp + 4 * q;
        const size_t gb = ((size_t)b * DD + d) * LL + l;
        bf16x4 qc4 = *(const bf16x4*)&qcT[gb];
        bf16x4 kv4 = *(const bf16x4*)&kv_ls[2112 * b + 48 + l];
        bf16x4 o;
#pragma unroll
        for (int r = 0; r < 4; r++) {
            float val = (acc[s][r] + (float)kv4[r] * dsk) * (float)qc4[r];
            o[r] = (bf16)val;
        }
        *(bf16x4*)&ygT[gb] = o;
    }
}

// ---------------------------------------------------------------------------
// bf16 transpose (B, D, L) -> (B, L, D), 64x64 tiles, fully vectorized:
// bf16x8 global loads (2 rows/thread -> full 64-row tile), XOR-swizzled LDS
// (conflict-free b128 writes, 2-way scalar reads = free), bf16x8 stores.
// ---------------------------------------------------------------------------
__global__ __launch_bounds__(256) void transpose_dl(const bf16* __restrict__ src,
                                                    bf16* __restrict__ dst) {
    __shared__ bf16 ts[64 * 64]; // 8 KB, row r holds d0+r, l-chunks XOR-swizzled
    const int b = blockIdx.z;
    const int l0 = blockIdx.x * 64, d0 = blockIdx.y * 64;
    const int tid = threadIdx.x;
    {
        const int r0 = tid >> 3, c8 = tid & 7; // row = d, 8 l-chunks of 8
#pragma unroll
        for (int h = 0; h < 2; h++) {
            const int r = r0 + h * 32;
            bf16x8 v = *(const bf16x8*)&src[((size_t)b * DD + d0 + r) * LL + l0 + c8 * 8];
            *(bf16x8*)&ts[r * 64 + ((c8 ^ (r & 7)) << 3)] = v;
        }
    }
    __syncthreads();
    const int l = tid & 63, dc0 = (tid >> 6) << 3;
#pragma unroll
    for (int half = 0; half < 2; half++) {
        const int dc = dc0 + half * 32;
        bf16x8 o;
#pragma unroll
        for (int j = 0; j < 8; j++) {
            const int r = dc + j;
            o[j] = ts[r * 64 + (((l >> 3) ^ (r & 7)) << 3) + (l & 7)];
        }
        *(bf16x8*)&dst[((size_t)b * LL + l0 + l) * DD + d0 + dc] = o;
    }
}

// ---------------------------------------------------------------------------
// launch
// ---------------------------------------------------------------------------
extern "C" void kernel_launch(void* const* d_in, const int* in_sizes, int n_in,
                              void* d_out, int out_size, void* d_ws, size_t ws_size,
                              hipStream_t stream) {
    const float* u   = (const float*)d_in[0];
    const float* Wq  = (const float*)d_in[1];
    const float* bq  = (const float*)d_in[2];
    const float* Wk  = (const float*)d_in[3];
    const float* bk  = (const float*)d_in[4];
    const float* Wv  = (const float*)d_in[5];
    const float* bv  = (const float*)d_in[6];
    const float* cqw = (const float*)d_in[7];
    const float* cqb = (const float*)d_in[8];
    const float* ckw = (const float*)d_in[9];
    const float* ckb = (const float*)d_in[10];
    const float* ssm = (const float*)d_in[11];
    const float* Dsk = (const float*)d_in[12];
    const float* Wo  = (const float*)d_in[13];
    const float* bo  = (const float*)d_in[14];

    char* w = (char*)d_ws;
    bf16* u_bf    = (bf16*)(w);                  // 33.55 MB (reused as ygT)
    bf16* Wqkv_bf = (bf16*)(w + 33554432ull);    // 25.2 MB (q|k|v rows concat)
    bf16* Wo_bf   = (bf16*)(w + 58720256ull);    // 8.39 MB
    bf16* qkvT    = (bf16*)(w + 67108864ull);    // 100.7 MB (6144 x 8192)
    bf16* qcT     = (bf16*)(w + 167772160ull);   // 33.55 MB
    bf16* kvT     = (bf16*)(w + 201326592ull);   // 33.55 MB
    // total: 234,881,024 B

    // fused fp32 -> bf16 conversions (u, Wq|Wk|Wv, Wo) in one launch
    cvt_all<<<16384, 256, 0, stream>>>(u, Wq, Wk, Wv, Wo, u_bf, Wqkv_bf, Wo_bf);

    // fused q/k/v projection -> transposed output (E, B*L); 768 wg, 8 waves
    gemm_qkv<<<(MM / 256) * (NN / 256), 512, 0, stream>>>(u_bf, Wqkv_bf, bq, bk, bv, qkvT);

    // depthwise convs + kv (row-wise on transposed layout)
    dwconv_kv2<<<BB * DD, 256, 0, stream>>>(qkvT, cqw, cqb, ckw, ckb, qcT, kvT);

    // causal long conv (Toeplitz MFMA) + gating
    bf16* ygT = u_bf; // reuse
    longconv_gate<<<DD, 128, 0, stream>>>(kvT, qcT, ssm, Dsk, ygT);

    // transpose back to (B,L,E)
    bf16* ygTT = qkvT; // reuse
    dim3 gc(LL / 64, DD / 64, BB);
    transpose_dl<<<gc, 256, 0, stream>>>(ygT, ygTT);

    // output projection -> fp32 d_out; 256 wg, 8 waves
    gemm_bt_f32<<<(MM / 256) * (DD / 256), 512, 0, stream>>>(ygTT, Wo_bf, bo,
                                                             (float*)d_out, DD, DD);
}